// Round 18
// baseline (175.002 us; speedup 1.0000x reference)
//
#include <hip/hip_runtime.h>

typedef short bf16x8 __attribute__((ext_vector_type(8)));
typedef float f32x4 __attribute__((ext_vector_type(4)));
typedef unsigned short ushort8v __attribute__((ext_vector_type(8)));
typedef unsigned short ushort4v __attribute__((ext_vector_type(4)));

__device__ __forceinline__ unsigned short f2bf(float f) {
  unsigned u = __float_as_uint(f);
  u += 0x7FFF + ((u >> 16) & 1);   // round-to-nearest-even
  return (unsigned short)(u >> 16);
}

// ---------------------------------------------------------------------------
// Kernel 0: weights -> WbT [640][512] bf16 (Wq pre-scaled by log2e).
// ---------------------------------------------------------------------------
__global__ void wt_prep(const float* __restrict__ Wq, const float* __restrict__ Wk,
                        const float* __restrict__ Wv, unsigned short* __restrict__ WbT) {
  int idx = blockIdx.x * 256 + threadIdx.x;   // 640*512 = 327680 total
  int o = idx >> 9, c = idx & 511;
  float v;
  if (o < 64)       v = Wq[c * 64 + o] * 1.44269504f;
  else if (o < 128) v = Wk[c * 64 + (o - 64)];
  else              v = Wv[(size_t)c * 512 + (o - 128)];
  WbT[idx] = f2bf(v);
}

// ---------------------------------------------------------------------------
// Kernel 1: projection GEMM  [16384,512] x [512,640] -> q,k row-major bf16 and
// v transposed vT[b][512][4096] bf16. (validated rounds 3-17, unchanged)
// ---------------------------------------------------------------------------
__global__ __launch_bounds__(256, 2) void proj_gemm(
    const float* __restrict__ x, const unsigned short* __restrict__ WbT,
    unsigned short* __restrict__ q, unsigned short* __restrict__ k,
    unsigned short* __restrict__ vT) {
  __shared__ unsigned short As[128][72];   // 64 + 8 pad
  const int tid = threadIdx.x;
  const int wid = tid >> 6, lane = tid & 63;
  const int l15 = lane & 15, l4 = lane >> 4;
  const int mtile = blockIdx.x, ntile = blockIdx.y;
  const int rbase = mtile * 128;
  const int wr = (wid >> 1) * 64, wc = (wid & 1) * 64;

  f32x4 acc[4][4] = {};

  const int arow = tid >> 2;         // 0..63
  const int akof = (tid & 3) * 16;   // 0,16,32,48

  for (int kb = 0; kb < 512; kb += 64) {
    f32x4 t0[2][4];
#pragma unroll
    for (int pass = 0; pass < 2; ++pass) {
      const float* src = x + (size_t)(rbase + pass * 64 + arow) * 512 + kb + akof;
#pragma unroll
      for (int i = 0; i < 4; ++i) t0[pass][i] = *(const f32x4*)(src + i * 4);
    }
    __syncthreads();
#pragma unroll
    for (int pass = 0; pass < 2; ++pass) {
      unsigned short tmp[16];
#pragma unroll
      for (int i = 0; i < 4; ++i)
#pragma unroll
        for (int j = 0; j < 4; ++j) tmp[i * 4 + j] = f2bf(t0[pass][i][j]);
      unsigned short* dst = &As[pass * 64 + arow][akof];
      *(ushort8v*)(dst)     = *(ushort8v*)(tmp);
      *(ushort8v*)(dst + 8) = *(ushort8v*)(tmp + 8);
    }
    __syncthreads();

    bf16x8 af[4][2], bfr[4][2];
#pragma unroll
    for (int mr = 0; mr < 4; ++mr)
#pragma unroll
      for (int ks = 0; ks < 2; ++ks)
        af[mr][ks] = *(const bf16x8*)&As[wr + mr * 16 + l15][ks * 32 + l4 * 8];
#pragma unroll
    for (int nc = 0; nc < 4; ++nc)
#pragma unroll
      for (int ks = 0; ks < 2; ++ks) {
        int col = ntile * 128 + wc + nc * 16 + l15;
        bfr[nc][ks] = *(const bf16x8*)(WbT + (size_t)col * 512 + kb + ks * 32 + l4 * 8);
      }
#pragma unroll
    for (int ks = 0; ks < 2; ++ks)
#pragma unroll
      for (int mr = 0; mr < 4; ++mr)
#pragma unroll
        for (int nc = 0; nc < 4; ++nc)
          acc[mr][nc] = __builtin_amdgcn_mfma_f32_16x16x32_bf16(af[mr][ks], bfr[nc][ks],
                                                                acc[mr][nc], 0, 0, 0);
  }

  if (ntile == 0) {
    unsigned short* dst = (wid & 1) ? k : q;
#pragma unroll
    for (int mr = 0; mr < 4; ++mr)
#pragma unroll
      for (int nc = 0; nc < 4; ++nc)
#pragma unroll
        for (int r = 0; r < 4; ++r) {
          int grow = rbase + wr + mr * 16 + l4 * 4 + r;
          int col = nc * 16 + l15;
          dst[(size_t)grow * 64 + col] = f2bf(acc[mr][nc][r]);
        }
  } else {
#pragma unroll
    for (int mr = 0; mr < 4; ++mr)
#pragma unroll
      for (int nc = 0; nc < 4; ++nc) {
        int col = ntile * 128 + wc + nc * 16 + l15 - 128;   // 0..511
        int grow = rbase + wr + mr * 16 + l4 * 4;
        int b = grow >> 12, m = grow & 4095;
        ushort4v pk;
#pragma unroll
        for (int r = 0; r < 4; ++r) pk[r] = f2bf(acc[mr][nc][r]);
        *(ushort4v*)(vT + ((size_t)b * 512 + col) * 4096 + m) = pk;
      }
  }
}

// ---------------------------------------------------------------------------
// Kernel 2 (v17): fused sigmoid-attention = v16's proven 1-barrier dbuf
// template + fragment-major layouts, at QBLK=64 so TWO independent blocks
// fit per CU (80 KB LDS each) -> cross-block MFMA/VALU phase overlap (the
// only mechanism that measured >85% pipe-sum, v9) with ZERO work inflation
// (rt-split: S per-row, no redundancy; only V staging duplicated, L2-shared).
// Grid (64 rt, 2 ct, 4 b) = 512 blocks x 512 threads (8 waves), 2 blocks/CU.
// Per chunk: loads(it+1)@top -> S(it) [K,Q regs] -> sigmoid -> Pwrite ->
// BARRIER -> PV(it) -> Vwrite(it+1). Ps/Vs double-buffered fragment-major.
// PV: wave owns cols w*32..+32 (oacc[4][2], fits 128-reg cap @4waves/SIMD).
// ---------------------------------------------------------------------------
__global__ __launch_bounds__(512, 4) void attn_fused(
    const float* __restrict__ x, const unsigned short* __restrict__ q,
    const unsigned short* __restrict__ k, const unsigned short* __restrict__ vT,
    const float* __restrict__ gamma, float* __restrict__ out) {
  __shared__ unsigned short Vs[2][16][8][16][8];   // 64 KB [buf][cf][s][l15][e]
  __shared__ unsigned short Ps[2][4][8][16][8];    // 16 KB [buf][f][s][l15][e]
  const int tid = threadIdx.x, w = tid >> 6, lane = tid & 63;
  const int l15 = lane & 15, l4 = lane >> 4;
  const int rh = w >> 2;         // S: row-frag pair group (0..1)
  const int mt = w & 3;          // S: m-tile (0..3)
  const int rt = blockIdx.x, ct = blockIdx.y, b = blockIdx.z;
  const int rbase = rt * 64, cbase = ct * 256;
  const unsigned short* qb = q + (size_t)b * 4096 * 64;
  const unsigned short* kp = k + (size_t)b * 4096 * 64;
  const unsigned short* vb = vT + (size_t)b * 512 * 4096;
  const float gv = gamma[0];
  const int vst_c = tid >> 1, vhalf = tid & 1;   // V staging: 64 B/thread

  // q fragments: wave's 2 row-frags (rows rh*32 .. +32), register-resident
  bf16x8 qf[2][2];
#pragma unroll
  for (int j = 0; j < 2; ++j)
#pragma unroll
    for (int ks = 0; ks < 2; ++ks)
      qf[j][ks] = *(const bf16x8*)(qb +
          (size_t)(rbase + (rh * 2 + j) * 16 + l15) * 64 + ks * 32 + l4 * 8);

  // ---- prologue: K(0) frags to regs; stage V(0) into Vs[0] ----
  bf16x8 kfc[2];
#pragma unroll
  for (int ks = 0; ks < 2; ++ks)
    kfc[ks] = *(const bf16x8*)(kp + (size_t)(mt * 16 + l15) * 64 + ks * 32 + l4 * 8);
  {
    bf16x8 vv[4];
#pragma unroll
    for (int i = 0; i < 4; ++i)
      vv[i] = *(const bf16x8*)(vb + (size_t)(cbase + vst_c) * 4096 + vhalf * 32 + i * 8);
#pragma unroll
    for (int i = 0; i < 4; ++i)
      *(bf16x8*)&Vs[0][vst_c >> 4][vhalf * 4 + i][vst_c & 15][0] = vv[i];
  }

  f32x4 oacc[4][2] = {};   // 64 rows x 32 cols (wave-private col group)

  for (int it = 0; it < 64; ++it) {
    const int mb_n = (it + 1) * 64;
    const bool pf = (it < 63);
    const int p = it & 1;
    bf16x8 kfn[2], vv[4];
    if (pf) {   // issue next chunk's loads; consumed a full chunk later
#pragma unroll
      for (int ks = 0; ks < 2; ++ks)
        kfn[ks] = *(const bf16x8*)(kp + (size_t)(mb_n + mt * 16 + l15) * 64 + ks * 32 + l4 * 8);
#pragma unroll
      for (int i = 0; i < 4; ++i)
        vv[i] = *(const bf16x8*)(vb + (size_t)(cbase + vst_c) * 4096 + mb_n + vhalf * 32 + i * 8);
    }

    // ---- S^T = K.Q^T : wave (rh,mt): m-tile mt (16 m) x rows rh*32(+32) ----
    f32x4 sacc[2] = {};
#pragma unroll
    for (int ks = 0; ks < 2; ++ks)
#pragma unroll
      for (int j = 0; j < 2; ++j)
        sacc[j] = __builtin_amdgcn_mfma_f32_16x16x32_bf16(kfc[ks], qf[j][ks], sacc[j], 0, 0, 0);

    // ---- sigmoid (q pre-scaled by log2e) + pack -> b64 P write ----
#pragma unroll
    for (int j = 0; j < 2; ++j) {
      ushort4v pk;
#pragma unroll
      for (int r = 0; r < 4; ++r) {
        float s = sacc[j][r];
        pk[r] = f2bf(__builtin_amdgcn_rcpf(1.0f + __builtin_amdgcn_exp2f(-s)));
      }
      *(ushort4v*)&Ps[p][rh * 2 + j][mt * 2 + (l4 >> 1)][l15][(l4 & 1) * 4] = pk;
    }
    __syncthreads();   // the ONLY barrier per chunk

    // ---- PV(it): O += P.v, wave cols w*32..+32, all 64 rows ----
    __builtin_amdgcn_s_setprio(1);
#pragma unroll
    for (int kk = 0; kk < 2; ++kk) {
      bf16x8 af[4], bfr[2];
#pragma unroll
      for (int mr = 0; mr < 4; ++mr)
        af[mr] = *(const bf16x8*)&Ps[p][mr][kk * 4 + l4][l15][0];
#pragma unroll
      for (int nc = 0; nc < 2; ++nc)
        bfr[nc] = *(const bf16x8*)&Vs[p][w * 2 + nc][kk * 4 + l4][l15][0];
#pragma unroll
      for (int mr = 0; mr < 4; ++mr)
#pragma unroll
        for (int nc = 0; nc < 2; ++nc)
          oacc[mr][nc] = __builtin_amdgcn_mfma_f32_16x16x32_bf16(af[mr], bfr[nc],
                                                                 oacc[mr][nc], 0, 0, 0);
    }
    __builtin_amdgcn_s_setprio(0);

    // ---- write prefetched V(it+1) into other buffer; rotate K frags ----
    if (pf) {
#pragma unroll
      for (int i = 0; i < 4; ++i)
        *(bf16x8*)&Vs[p ^ 1][vst_c >> 4][vhalf * 4 + i][vst_c & 15][0] = vv[i];
      kfc[0] = kfn[0]; kfc[1] = kfn[1];
    }
  }

  // ---- epilogue: out = gamma * O + x (no reduction needed) ----
#pragma unroll
  for (int mr = 0; mr < 4; ++mr)
#pragma unroll
    for (int nc = 0; nc < 2; ++nc)
#pragma unroll
      for (int r = 0; r < 4; ++r) {
        int grow = rbase + mr * 16 + l4 * 4 + r;
        int col = cbase + w * 32 + nc * 16 + l15;
        size_t idx = ((size_t)b * 4096 + grow) * 512 + col;
        out[idx] = gv * oacc[mr][nc][r] + x[idx];
      }
}

extern "C" void kernel_launch(void* const* d_in, const int* in_sizes, int n_in,
                              void* d_out, int out_size, void* d_ws, size_t ws_size,
                              hipStream_t stream) {
  const float* x     = (const float*)d_in[0];
  const float* Wq    = (const float*)d_in[1];
  const float* Wk    = (const float*)d_in[2];
  const float* Wv    = (const float*)d_in[3];
  const float* gamma = (const float*)d_in[4];
  float* out = (float*)d_out;

  char* ws = (char*)d_ws;
  unsigned short* qbuf = (unsigned short*)(ws);                       // 2 MB
  unsigned short* kbuf = (unsigned short*)(ws + (2ull << 20));        // 2 MB
  unsigned short* vT   = (unsigned short*)(ws + (4ull << 20));        // 16 MB
  unsigned short* WbT  = (unsigned short*)(ws + (20ull << 20));       // 640 KB

  hipLaunchKernelGGL(wt_prep, dim3(1280), dim3(256), 0, stream, Wq, Wk, Wv, WbT);
  hipLaunchKernelGGL(proj_gemm, dim3(128, 5), dim3(256), 0, stream, x, WbT, qbuf, kbuf, vT);
  hipLaunchKernelGGL(attn_fused, dim3(64, 2, 4), dim3(512), 0, stream,
                     x, qbuf, kbuf, vT, gamma, out);
}

// Round 19
// 141.985 us; speedup vs baseline: 1.2325x; 1.2325x over previous
//
#include <hip/hip_runtime.h>

typedef short bf16x8 __attribute__((ext_vector_type(8)));
typedef float f32x4 __attribute__((ext_vector_type(4)));
typedef unsigned short ushort8v __attribute__((ext_vector_type(8)));
typedef unsigned short ushort4v __attribute__((ext_vector_type(4)));

__device__ __forceinline__ unsigned short f2bf(float f) {
  unsigned u = __float_as_uint(f);
  u += 0x7FFF + ((u >> 16) & 1);   // round-to-nearest-even
  return (unsigned short)(u >> 16);
}

// ---------------------------------------------------------------------------
// Kernel 0: weights -> WbT [640][512] bf16 (Wq pre-scaled by log2e).
// ---------------------------------------------------------------------------
__global__ void wt_prep(const float* __restrict__ Wq, const float* __restrict__ Wk,
                        const float* __restrict__ Wv, unsigned short* __restrict__ WbT) {
  int idx = blockIdx.x * 256 + threadIdx.x;   // 640*512 = 327680 total
  int o = idx >> 9, c = idx & 511;
  float v;
  if (o < 64)       v = Wq[c * 64 + o] * 1.44269504f;
  else if (o < 128) v = Wk[c * 64 + (o - 64)];
  else              v = Wv[(size_t)c * 512 + (o - 128)];
  WbT[idx] = f2bf(v);
}

// ---------------------------------------------------------------------------
// Kernel 1: projection GEMM  [16384,512] x [512,640] -> q,k row-major bf16 and
// v transposed vT[b][512][4096] bf16. (validated rounds 3-18, unchanged)
// ---------------------------------------------------------------------------
__global__ __launch_bounds__(256, 2) void proj_gemm(
    const float* __restrict__ x, const unsigned short* __restrict__ WbT,
    unsigned short* __restrict__ q, unsigned short* __restrict__ k,
    unsigned short* __restrict__ vT) {
  __shared__ unsigned short As[128][72];   // 64 + 8 pad
  const int tid = threadIdx.x;
  const int wid = tid >> 6, lane = tid & 63;
  const int l15 = lane & 15, l4 = lane >> 4;
  const int mtile = blockIdx.x, ntile = blockIdx.y;
  const int rbase = mtile * 128;
  const int wr = (wid >> 1) * 64, wc = (wid & 1) * 64;

  f32x4 acc[4][4] = {};

  const int arow = tid >> 2;         // 0..63
  const int akof = (tid & 3) * 16;   // 0,16,32,48

  for (int kb = 0; kb < 512; kb += 64) {
    f32x4 t0[2][4];
#pragma unroll
    for (int pass = 0; pass < 2; ++pass) {
      const float* src = x + (size_t)(rbase + pass * 64 + arow) * 512 + kb + akof;
#pragma unroll
      for (int i = 0; i < 4; ++i) t0[pass][i] = *(const f32x4*)(src + i * 4);
    }
    __syncthreads();
#pragma unroll
    for (int pass = 0; pass < 2; ++pass) {
      unsigned short tmp[16];
#pragma unroll
      for (int i = 0; i < 4; ++i)
#pragma unroll
        for (int j = 0; j < 4; ++j) tmp[i * 4 + j] = f2bf(t0[pass][i][j]);
      unsigned short* dst = &As[pass * 64 + arow][akof];
      *(ushort8v*)(dst)     = *(ushort8v*)(tmp);
      *(ushort8v*)(dst + 8) = *(ushort8v*)(tmp + 8);
    }
    __syncthreads();

    bf16x8 af[4][2], bfr[4][2];
#pragma unroll
    for (int mr = 0; mr < 4; ++mr)
#pragma unroll
      for (int ks = 0; ks < 2; ++ks)
        af[mr][ks] = *(const bf16x8*)&As[wr + mr * 16 + l15][ks * 32 + l4 * 8];
#pragma unroll
    for (int nc = 0; nc < 4; ++nc)
#pragma unroll
      for (int ks = 0; ks < 2; ++ks) {
        int col = ntile * 128 + wc + nc * 16 + l15;
        bfr[nc][ks] = *(const bf16x8*)(WbT + (size_t)col * 512 + kb + ks * 32 + l4 * 8);
      }
#pragma unroll
    for (int ks = 0; ks < 2; ++ks)
#pragma unroll
      for (int mr = 0; mr < 4; ++mr)
#pragma unroll
        for (int nc = 0; nc < 4; ++nc)
          acc[mr][nc] = __builtin_amdgcn_mfma_f32_16x16x32_bf16(af[mr][ks], bfr[nc][ks],
                                                                acc[mr][nc], 0, 0, 0);
  }

  if (ntile == 0) {
    unsigned short* dst = (wid & 1) ? k : q;
#pragma unroll
    for (int mr = 0; mr < 4; ++mr)
#pragma unroll
      for (int nc = 0; nc < 4; ++nc)
#pragma unroll
        for (int r = 0; r < 4; ++r) {
          int grow = rbase + wr + mr * 16 + l4 * 4 + r;
          int col = nc * 16 + l15;
          dst[(size_t)grow * 64 + col] = f2bf(acc[mr][nc][r]);
        }
  } else {
#pragma unroll
    for (int mr = 0; mr < 4; ++mr)
#pragma unroll
      for (int nc = 0; nc < 4; ++nc) {
        int col = ntile * 128 + wc + nc * 16 + l15 - 128;   // 0..511
        int grow = rbase + wr + mr * 16 + l4 * 4;
        int b = grow >> 12, m = grow & 4095;
        ushort4v pk;
#pragma unroll
        for (int r = 0; r < 4; ++r) pk[r] = f2bf(acc[mr][nc][r]);
        *(ushort4v*)(vT + ((size_t)b * 512 + col) * 4096 + m) = pk;
      }
  }
}

// ---------------------------------------------------------------------------
// Kernel 2 (v16, re-landed best): fused sigmoid-attention = v12's proven
// schedule with FRAGMENT-MAJOR LDS layouts (conflict-reduced by construction).
// Layouts: Ps[buf][qfrag 0..7][mseg 0..7][l15][8], Vs[buf][colfrag 0..15]
// [mseg 0..7][l15][8] -> every PV wave read = 1KB contiguous (b128 floor);
// P b64 writes at 4/bank floor; V staging writes at 8/bank floor.
// Grid (32 rt, 2 ct, 4 b) = 256 blocks x 512 threads (8 waves), 1 block/CU.
// Chunk loop: loads(it+1)@top -> S(it) [K,Q regs] -> sigmoid -> Pwrite ->
// BARRIER -> PV(it) [m-split pair tiling] -> Vwrite(it+1).
// Epilogue: LDS pair-reduction (ms=1 -> ms=0), aliases Vs (64KB exact).
// LDS 96 KB. Measured R17: attn 117 us, total 142.2, absmax 0.5.
// ---------------------------------------------------------------------------
__global__ __launch_bounds__(512, 1) void attn_fused(
    const float* __restrict__ x, const unsigned short* __restrict__ q,
    const unsigned short* __restrict__ k, const unsigned short* __restrict__ vT,
    const float* __restrict__ gamma, float* __restrict__ out) {
  __shared__ unsigned short Vs[2][16][8][16][8];   // 64 KB [buf][cf][s][l15][e]
  __shared__ unsigned short Ps[2][8][8][16][8];    // 32 KB [buf][f][s][l15][e]
  const int tid = threadIdx.x, w = tid >> 6, lane = tid & 63;
  const int l15 = lane & 15, l4 = lane >> 4;
  const int rhalf = w >> 2;      // S: q-row half
  const int mt = w & 3;          // S: m-tile
  const int pvt = w >> 1;        // PV: col-group (0..3)
  const int ms = w & 1;          // PV: m-half (0..1)
  const int rt = blockIdx.x, ct = blockIdx.y, b = blockIdx.z;
  const int rbase = rt * 128, cbase = ct * 256;
  const unsigned short* qb = q + (size_t)b * 4096 * 64;
  const unsigned short* kp = k + (size_t)b * 4096 * 64;
  const unsigned short* vb = vT + (size_t)b * 512 * 4096;
  const float gv = gamma[0];
  const int vst_c = tid >> 1, vhalf = tid & 1;   // V staging: 64 B/thread

  // q fragments, register-resident
  bf16x8 qf[4][2];
#pragma unroll
  for (int rf = 0; rf < 4; ++rf)
#pragma unroll
    for (int ks = 0; ks < 2; ++ks)
      qf[rf][ks] = *(const bf16x8*)(qb +
          (size_t)(rbase + rhalf * 64 + rf * 16 + l15) * 64 + ks * 32 + l4 * 8);

  // ---- prologue: K(0) frags to regs; stage V(0) into Vs[0] ----
  bf16x8 kfc[2];
#pragma unroll
  for (int ks = 0; ks < 2; ++ks)
    kfc[ks] = *(const bf16x8*)(kp + (size_t)(mt * 16 + l15) * 64 + ks * 32 + l4 * 8);
  {
    bf16x8 vv[4];
#pragma unroll
    for (int i = 0; i < 4; ++i)
      vv[i] = *(const bf16x8*)(vb + (size_t)(cbase + vst_c) * 4096 + vhalf * 32 + i * 8);
#pragma unroll
    for (int i = 0; i < 4; ++i)
      *(bf16x8*)&Vs[0][vst_c >> 4][vhalf * 4 + i][vst_c & 15][0] = vv[i];
  }

  f32x4 oacc[8][4] = {};   // 128 rows x 64 cols partial (m-half ms)

  for (int it = 0; it < 64; ++it) {
    const int mb_n = (it + 1) * 64;
    const bool pf = (it < 63);
    const int p = it & 1;
    bf16x8 kfn[2], vv[4];
    if (pf) {   // issue next chunk's loads; consumed a full chunk later
#pragma unroll
      for (int ks = 0; ks < 2; ++ks)
        kfn[ks] = *(const bf16x8*)(kp + (size_t)(mb_n + mt * 16 + l15) * 64 + ks * 32 + l4 * 8);
#pragma unroll
      for (int i = 0; i < 4; ++i)
        vv[i] = *(const bf16x8*)(vb + (size_t)(cbase + vst_c) * 4096 + mb_n + vhalf * 32 + i * 8);
    }

    // ---- S^T = K.Q^T : wave (rhalf,mt): m-tile mt (16 m) x 64 q-rows ----
    f32x4 sacc[4] = {};
#pragma unroll
    for (int ks = 0; ks < 2; ++ks)
#pragma unroll
      for (int rf = 0; rf < 4; ++rf)
        sacc[rf] = __builtin_amdgcn_mfma_f32_16x16x32_bf16(kfc[ks], qf[rf][ks], sacc[rf], 0, 0, 0);

    // ---- sigmoid (q pre-scaled by log2e) + pack -> b64 P write ----
#pragma unroll
    for (int rf = 0; rf < 4; ++rf) {
      ushort4v pk;
#pragma unroll
      for (int r = 0; r < 4; ++r) {
        float s = sacc[rf][r];
        pk[r] = f2bf(__builtin_amdgcn_rcpf(1.0f + __builtin_amdgcn_exp2f(-s)));
      }
      *(ushort4v*)&Ps[p][rhalf * 4 + rf][mt * 2 + (l4 >> 1)][l15][(l4 & 1) * 4] = pk;
    }
    __syncthreads();   // the ONLY barrier per chunk

    // ---- PV(it): tile 128 rows x 64 cols (pvt), m-slice ms*32..+32 ----
    __builtin_amdgcn_s_setprio(1);
    {
      bf16x8 af[8], bfr[4];
#pragma unroll
      for (int mr = 0; mr < 8; ++mr)
        af[mr] = *(const bf16x8*)&Ps[p][mr][ms * 4 + l4][l15][0];
#pragma unroll
      for (int nc = 0; nc < 4; ++nc)
        bfr[nc] = *(const bf16x8*)&Vs[p][pvt * 4 + nc][ms * 4 + l4][l15][0];
#pragma unroll
      for (int mr = 0; mr < 8; ++mr)
#pragma unroll
        for (int nc = 0; nc < 4; ++nc)
          oacc[mr][nc] = __builtin_amdgcn_mfma_f32_16x16x32_bf16(af[mr], bfr[nc],
                                                                 oacc[mr][nc], 0, 0, 0);
    }
    __builtin_amdgcn_s_setprio(0);

    // ---- write prefetched V(it+1) into other buffer; rotate K frags ----
    if (pf) {
#pragma unroll
      for (int i = 0; i < 4; ++i)
        *(bf16x8*)&Vs[p ^ 1][vst_c >> 4][vhalf * 4 + i][vst_c & 15][0] = vv[i];
      kfc[0] = kfn[0]; kfc[1] = kfn[1];
    }
  }

  // ---- epilogue: pair-reduce (ms=1 -> ms=0) via LDS, then gamma*O + x ----
  float* red = (float*)&Vs[0][0][0][0][0];   // 4 tiles x 64 rows x 64 cols f32 = 64 KB
  __syncthreads();   // chunk loop done; safe to reuse Vs
#pragma unroll
  for (int h = 0; h < 2; ++h) {
    if (ms == 1) {
#pragma unroll
      for (int m4 = 0; m4 < 4; ++m4)
#pragma unroll
        for (int nc = 0; nc < 4; ++nc)
#pragma unroll
          for (int r = 0; r < 4; ++r)
            red[(pvt * 64 + m4 * 16 + l4 * 4 + r) * 64 + nc * 16 + l15] =
                oacc[h * 4 + m4][nc][r];
    }
    __syncthreads();
    if (ms == 0) {
#pragma unroll
      for (int m4 = 0; m4 < 4; ++m4)
#pragma unroll
        for (int nc = 0; nc < 4; ++nc)
#pragma unroll
          for (int r = 0; r < 4; ++r) {
            int mr = h * 4 + m4;
            float sum = oacc[mr][nc][r] +
                red[(pvt * 64 + m4 * 16 + l4 * 4 + r) * 64 + nc * 16 + l15];
            int grow = rbase + mr * 16 + l4 * 4 + r;
            int col = cbase + pvt * 64 + nc * 16 + l15;
            size_t idx = ((size_t)b * 4096 + grow) * 512 + col;
            out[idx] = gv * sum + x[idx];
          }
    }
    __syncthreads();
  }
}

extern "C" void kernel_launch(void* const* d_in, const int* in_sizes, int n_in,
                              void* d_out, int out_size, void* d_ws, size_t ws_size,
                              hipStream_t stream) {
  const float* x     = (const float*)d_in[0];
  const float* Wq    = (const float*)d_in[1];
  const float* Wk    = (const float*)d_in[2];
  const float* Wv    = (const float*)d_in[3];
  const float* gamma = (const float*)d_in[4];
  float* out = (float*)d_out;

  char* ws = (char*)d_ws;
  unsigned short* qbuf = (unsigned short*)(ws);                       // 2 MB
  unsigned short* kbuf = (unsigned short*)(ws + (2ull << 20));        // 2 MB
  unsigned short* vT   = (unsigned short*)(ws + (4ull << 20));        // 16 MB
  unsigned short* WbT  = (unsigned short*)(ws + (20ull << 20));       // 640 KB

  hipLaunchKernelGGL(wt_prep, dim3(1280), dim3(256), 0, stream, Wq, Wk, Wv, WbT);
  hipLaunchKernelGGL(proj_gemm, dim3(128, 5), dim3(256), 0, stream, x, WbT, qbuf, kbuf, vT);
  hipLaunchKernelGGL(attn_fused, dim3(32, 2, 4), dim3(512), 0, stream,
                     x, qbuf, kbuf, vT, gamma, out);
}